// Round 11
// baseline (355.684 us; speedup 1.0000x reference)
//
#include <hip/hip_runtime.h>
#include <hip/hip_bf16.h>
#include <hip/hip_fp16.h>

#define NN 100000
#define NE 1600000
#define FIN 128
#define HD 64
#define NB_MF 1563     // ceil(NN/64): 64-row tiles
#define BSH 8          // bucket covers 256 dest nodes (32KB preB tile)
#define BUCK 256
#define NBUCK 392      // ceil(NN/256)=391, padded to 392 so NEB=784=8*98 (bijective XCD swizzle)
#define BCAP 5120      // per-bucket staging cap (mean 4082, sigma 64 -> +16 sigma)
#define CHUNK 4096     // edges per stage-1 block (391 blocks; LDS counting sort per block)
#define NCHUNK 391     // ceil(NE/CHUNK)
#define ESPLIT 2       // edge-kernel blocks per bucket
#define NEB (NBUCK*ESPLIT)   // 784 = 8*98 (XCD-swizzlable)
#define NFB 6250       // k_final blocks: 6250*256 = NE exactly

typedef unsigned int uint32;
typedef _Float16 half8 __attribute__((ext_vector_type(8)));
typedef float f32x4 __attribute__((ext_vector_type(4)));
typedef float f32x8 __attribute__((ext_vector_type(8)));

// ---------------- fused launch 1: k_pp = k_part (blocks 0..390) + prep (blocks 391..487) ----------
__global__ void __launch_bounds__(256) k_pp(const int* __restrict__ row,
                                            const int* __restrict__ col,
                                            int* __restrict__ bcnt,
                                            uint32* __restrict__ staged,
                                            uint32* __restrict__ posE,
                                            const float* __restrict__ encW, const float* __restrict__ c1W,
                                            const float* __restrict__ c2W, const float* __restrict__ ep1W,
                                            _Float16* __restrict__ wt,
                                            const float* __restrict__ encB, const float* __restrict__ encG,
                                            const float* __restrict__ encBe, const float* __restrict__ encM,
                                            const float* __restrict__ encV,
                                            const float* __restrict__ ep1b, const float* __restrict__ epG,
                                            const float* __restrict__ epBe, const float* __restrict__ epM,
                                            const float* __restrict__ epV,
                                            float* __restrict__ foldEnc, float* __restrict__ foldPre,
                                            _Float16* __restrict__ bufBzero,
                                            _Float16* __restrict__ bufB2zero){
    int blk = blockIdx.x, t = threadIdx.x;
    if(blk < NCHUNK){
        // ---- k_part body: LDS counting sort -> coalesced run writes ----
        __shared__ int h[512];
        __shared__ int sc[512];
        __shared__ int gb[512];
        __shared__ uint32 lcsr[CHUNK];
        __shared__ int dst[CHUNK];
        int e0 = blk * CHUNK;
        int e1 = min(e0 + CHUNK, NE);
        h[t] = 0; h[256+t] = 0;
        __syncthreads();
        for(int e = e0 + t; e < e1; e += 256)
            atomicAdd(&h[col[e] >> BSH], 1);
        __syncthreads();
        int c0 = h[t], c1 = h[256+t];
        int i2 = 256 + t;
        gb[t]  = (c0 > 0) ? atomicAdd(&bcnt[t], c0) : 0;
        gb[i2] = (i2 < NBUCK && c1 > 0) ? atomicAdd(&bcnt[i2], c1) : 0;
        sc[t] = c0; __syncthreads();
        for(int off = 1; off < 256; off <<= 1){
            int a = (t >= off) ? sc[t-off] : 0;
            __syncthreads();
            sc[t] += a;
            __syncthreads();
        }
        int sum0 = sc[255];
        __syncthreads();
        sc[i2] = c1; __syncthreads();
        for(int off = 1; off < 256; off <<= 1){
            int a = (t >= off) ? sc[i2-off] : 0;
            __syncthreads();
            sc[i2] += a;
            __syncthreads();
        }
        __syncthreads();
        {
            int st0 = sc[t] - c0;
            int st1 = sc[i2] + sum0 - c1;
            h[t]   = st0;
            h[i2]  = st1;
            sc[t]  = t*BCAP  + gb[t]  - st0;
            sc[i2] = i2*BCAP + gb[i2] - st1;
        }
        __syncthreads();
        for(int e = e0 + t; e < e1; e += 256){
            int c = col[e], r = row[e];
            int b = c >> BSH;
            int p = atomicAdd(&h[b], 1);
            lcsr[p] = ((uint32)r << BSH) | (uint32)(c & (BUCK-1));
            int slot = sc[b] + p;
            int off  = slot - b*BCAP;
            bool ok  = (off < BCAP);
            dst[p]   = ok ? slot : -1;
            posE[e]  = ok ? (uint32)slot : 0xFFFFFFFFu;
        }
        __syncthreads();
        int cnt = e1 - e0;
        for(int i = t; i < cnt; i += 256){
            int d = dst[i];
            if(d >= 0) staged[d] = lcsr[i];
        }
    } else {
        // ---- prep body ----
        int pblk = blk - NCHUNK;
        if(pblk < 96){
            int i = pblk*256 + t;   // 96*256 = 24576
            if(i < 8192){
                int n = i >> 7, k = i & 127;
                wt[i] = (_Float16)encW[k*64 + n];
            } else if(i < 12288){
                int j = i - 8192; int n = j >> 6, k = j & 63;
                wt[i] = (_Float16)c1W[k*64 + n];
            } else if(i < 16384){
                int j = i - 12288; int n = j >> 6, k = j & 63;
                wt[i] = (_Float16)c2W[k*64 + n];
            } else {
                int j = i - 16384; int hh = j >> 12; int jj = j & 4095;
                int n = jj >> 6, k = jj & 63;
                wt[i] = (_Float16)ep1W[(hh*64 + k)*64 + n];   // logical W[k][hh*64+n]
            }
        } else {
            if(t < 64){
                int j = t;
                float s = encG[j]*rsqrtf(encV[j]+1e-5f);
                foldEnc[j]      = s;
                foldEnc[64+j]   = (encB[j]-encM[j])*s + encBe[j];
                float sp = epG[j]*rsqrtf(epV[j]+1e-5f);
                foldPre[j]      = sp;
                foldPre[64+j]   = sp;
                foldPre[128+j]  = sp*(ep1b[j]-epM[j]) + epBe[j];
                foldPre[192+j]  = 0.f;
                bufBzero[j]     = (_Float16)0.f;   // dummy zero rows for gather clamp
                bufB2zero[j]    = (_Float16)0.f;
            }
        }
    }
}

// ---------------- fused launch 2: k_fe = k_fill3 (blocks 0..391) + encoder mfma (392..1954) ------
__global__ void __launch_bounds__(256) k_fe(const int* __restrict__ bcnt,
                                            const uint32* __restrict__ staged,
                                            int* __restrict__ deg,
                                            int* __restrict__ starts,
                                            float* __restrict__ dinv,
                                            int* __restrict__ csr,
                                            const float* __restrict__ x,
                                            const _Float16* __restrict__ wt,
                                            const float* __restrict__ foldEnc,
                                            _Float16* __restrict__ bufA){
    __shared__ union U {
        struct { int h[BUCK]; int sc[BUCK]; int red[256]; int lcsr[BCAP]; } f;   // 23KB
        struct { _Float16 As[64*136]; _Float16 Bs[64*136]; } m;                  // 34KB
    } sh;
    int blk = blockIdx.x, t = threadIdx.x;
    if(blk < NBUCK){
        // ---- fill3 body ----
        int b = blk;
        int part = 0;
        for(int i = t; i < b; i += 256) part += min(bcnt[i], BCAP);
        sh.f.red[t] = part; __syncthreads();
        for(int off = 128; off > 0; off >>= 1){
            if(t < off) sh.f.red[t] += sh.f.red[t+off];
            __syncthreads();
        }
        int base = sh.f.red[0];
        sh.f.h[t] = 0;
        __syncthreads();
        int cnt = min(bcnt[b], BCAP);
        const uint32* st = staged + (size_t)b*BCAP;
        for(int i = t; i < cnt; i += 256) atomicAdd(&sh.f.h[st[i] & (BUCK-1)], 1);
        __syncthreads();
        int v = sh.f.h[t];
        sh.f.sc[t] = v; __syncthreads();
        for(int off = 1; off < 256; off <<= 1){
            int a = (t >= off) ? sh.f.sc[t-off] : 0;
            __syncthreads();
            sh.f.sc[t] += a;
            __syncthreads();
        }
        int ex = sh.f.sc[t] - v;
        int n = b*BUCK + t;
        if(n < NN){
            deg[n]    = v;
            starts[n] = base + ex;
            dinv[n]   = rsqrtf((float)(v + 1));   // +1 self-loop
        }
        sh.f.h[t] = ex;
        __syncthreads();
        for(int i = t; i < cnt; i += 256){
            uint32 u = st[i];
            int p = atomicAdd(&sh.f.h[u & (BUCK-1)], 1);
            sh.f.lcsr[p] = (int)(u >> BSH);
        }
        __syncthreads();
        for(int i = t; i < cnt; i += 256) csr[base + i] = sh.f.lcsr[i];
    } else {
        // ---- encoder mfma body: K=128, A fp32 (cvt in stage), fold+relu, OS=64 ----
        constexpr int K = FIN, PS = K + 8;
        int m0 = (blk - NBUCK)*64;
        for(int idx = t; idx < 64*(K/8); idx += 256){
            int n = idx/(K/8), c = idx%(K/8);
            *(half8*)&sh.m.Bs[n*PS + c*8] = *(const half8*)&wt[n*K + c*8];
        }
        for(int idx = t; idx < 64*(K/4); idx += 256){
            int r = idx/(K/4), c = idx%(K/4);
            int rowi = m0 + r; if(rowi >= NN) rowi = NN-1;
            float4 v = *(const float4*)&x[(size_t)rowi*K + c*4];
            _Float16* d = &sh.m.As[r*PS + c*4];
            d[0]=(_Float16)v.x; d[1]=(_Float16)v.y; d[2]=(_Float16)v.z; d[3]=(_Float16)v.w;
        }
        __syncthreads();
        int w = t>>6, l = t&63;
        int lm = l&15, q = l>>4;
        f32x4 acc0 = {0.f,0.f,0.f,0.f}, acc1 = {0.f,0.f,0.f,0.f};
        f32x4 acc2 = {0.f,0.f,0.f,0.f}, acc3 = {0.f,0.f,0.f,0.f};
        const _Float16* arow = &sh.m.As[(w*16+lm)*PS + q*8];
        const _Float16* brow = &sh.m.Bs[lm*PS + q*8];
        #pragma unroll
        for(int ks = 0; ks < K/32; ks++){
            half8 a  = *(const half8*)(arow + ks*32);
            half8 b0 = *(const half8*)(brow + ks*32);
            half8 b1 = *(const half8*)(brow + 16*PS + ks*32);
            half8 b2 = *(const half8*)(brow + 32*PS + ks*32);
            half8 b3 = *(const half8*)(brow + 48*PS + ks*32);
            acc0 = __builtin_amdgcn_mfma_f32_16x16x32_f16(a, b0, acc0, 0,0,0);
            acc1 = __builtin_amdgcn_mfma_f32_16x16x32_f16(a, b1, acc1, 0,0,0);
            acc2 = __builtin_amdgcn_mfma_f32_16x16x32_f16(a, b2, acc2, 0,0,0);
            acc3 = __builtin_amdgcn_mfma_f32_16x16x32_f16(a, b3, acc3, 0,0,0);
        }
        f32x4 accs[4] = {acc0, acc1, acc2, acc3};
        #pragma unroll
        for(int nt = 0; nt < 4; nt++){
            int jcol = nt*16 + lm;
            float fs = foldEnc[jcol];
            float fb = foldEnc[64 + jcol];
            #pragma unroll
            for(int r = 0; r < 4; r++){
                int rowi = m0 + w*16 + q*4 + r;
                if(rowi >= NN) continue;
                float v = accs[nt][r]*fs + fb;
                v = fmaxf(v, 0.f);
                bufA[(size_t)rowi*64 + jcol] = (_Float16)v;
            }
        }
    }
}

// ---------------- MFMA GEMM (conv1 only): 64 rows x 64 cols, scale by dinv ----------------
__global__ void __launch_bounds__(256) k_mfc1(const _Float16* __restrict__ A,
                                              const _Float16* __restrict__ Bt,
                                              const float* __restrict__ rowscale,
                                              _Float16* __restrict__ outh){
    constexpr int K = 64, PS = K + 8;
    __shared__ _Float16 As[64*PS];
    __shared__ _Float16 Bs[64*PS];
    int t = threadIdx.x;
    int m0 = blockIdx.x*64;
    for(int idx = t; idx < 64*(K/8); idx += 256){
        int n = idx/(K/8), c = idx%(K/8);
        *(half8*)&Bs[n*PS + c*8] = *(const half8*)&Bt[n*K + c*8];
    }
    for(int idx = t; idx < 64*(K/8); idx += 256){
        int r = idx/(K/8), c = idx%(K/8);
        int rowi = m0 + r; if(rowi >= NN) rowi = NN-1;
        *(half8*)&As[r*PS + c*8] = *(const half8*)&A[(size_t)rowi*K + c*8];
    }
    __syncthreads();
    int w = t>>6, l = t&63;
    int lm = l&15, q = l>>4;
    f32x4 acc0 = {0.f,0.f,0.f,0.f}, acc1 = {0.f,0.f,0.f,0.f};
    f32x4 acc2 = {0.f,0.f,0.f,0.f}, acc3 = {0.f,0.f,0.f,0.f};
    const _Float16* arow = &As[(w*16+lm)*PS + q*8];
    const _Float16* brow = &Bs[lm*PS + q*8];
    #pragma unroll
    for(int ks = 0; ks < K/32; ks++){
        half8 a  = *(const half8*)(arow + ks*32);
        half8 b0 = *(const half8*)(brow + ks*32);
        half8 b1 = *(const half8*)(brow + 16*PS + ks*32);
        half8 b2 = *(const half8*)(brow + 32*PS + ks*32);
        half8 b3 = *(const half8*)(brow + 48*PS + ks*32);
        acc0 = __builtin_amdgcn_mfma_f32_16x16x32_f16(a, b0, acc0, 0,0,0);
        acc1 = __builtin_amdgcn_mfma_f32_16x16x32_f16(a, b1, acc1, 0,0,0);
        acc2 = __builtin_amdgcn_mfma_f32_16x16x32_f16(a, b2, acc2, 0,0,0);
        acc3 = __builtin_amdgcn_mfma_f32_16x16x32_f16(a, b3, acc3, 0,0,0);
    }
    f32x4 accs[4] = {acc0, acc1, acc2, acc3};
    #pragma unroll
    for(int nt = 0; nt < 4; nt++){
        int jcol = nt*16 + lm;
        #pragma unroll
        for(int r = 0; r < 4; r++){
            int rowi = m0 + w*16 + q*4 + r;
            if(rowi >= NN) continue;
            float v = accs[nt][r] * rowscale[rowi];
            outh[(size_t)rowi*64 + jcol] = (_Float16)v;
        }
    }
}

// ---------------- fused aggregation + GEMM ----------------
// Phase 1 (agg): block owns 64 nodes; wave w computes rows w*16..+15 in 4 groups of 4
// (exact k_agg4 inner loop -> bitwise-identical aggregation). Result h = relu((sum+self)*dinv+bias)
// goes DIRECTLY into LDS As (fp16) -- no global h round trip. Optional fp32 node_out write.
// Phase 2 (GEMM): h-tile @ Bt (NJH*64 cols). SCALE: *dinv[row] (conv). FOLD: foldPre (edge pre).
template<int NJH, bool SCALE, bool FOLD, bool WRITEF>
__global__ void __launch_bounds__(256) k_aggmm(const _Float16* __restrict__ hb,
                                               const int* __restrict__ starts,
                                               const int* __restrict__ deg,
                                               const int* __restrict__ csr,
                                               const float* __restrict__ dinv,
                                               const float* __restrict__ bias,
                                               const _Float16* __restrict__ Bt,
                                               const float* __restrict__ fold,
                                               float* __restrict__ outf,
                                               _Float16* __restrict__ outh){
    constexpr int K = 64, PS = K + 8;
    __shared__ _Float16 As[64*PS];
    __shared__ _Float16 Bs[NJH*64*PS];
    int t = threadIdx.x, w = t>>6, f = t&63;
    int m0 = blockIdx.x*64;
    // stage B (independent of agg)
    for(int idx = t; idx < NJH*64*8; idx += 256){
        int n = idx>>3, c = idx&7;
        *(half8*)&Bs[n*PS + c*8] = *(const half8*)&Bt[n*K + c*8];
    }
    // agg phase
    float bv = bias[f];
    for(int g = 0; g < 4; g++){
        int rb = w*16 + g*4;
        int na = min(m0+rb+0, NN-1), nb = min(m0+rb+1, NN-1);
        int nc = min(m0+rb+2, NN-1), nd = min(m0+rb+3, NN-1);
        int s0 = __builtin_amdgcn_readfirstlane(starts[na]);
        int s1 = __builtin_amdgcn_readfirstlane(starts[nb]);
        int s2 = __builtin_amdgcn_readfirstlane(starts[nc]);
        int s3 = __builtin_amdgcn_readfirstlane(starts[nd]);
        int d0 = __builtin_amdgcn_readfirstlane(deg[na]);
        int d1 = __builtin_amdgcn_readfirstlane(deg[nb]);
        int d2 = __builtin_amdgcn_readfirstlane(deg[nc]);
        int d3 = __builtin_amdgcn_readfirstlane(deg[nd]);
        float a0 = 0.f, a1 = 0.f, a2 = 0.f, a3 = 0.f;
        int dmax = max(max(d0,d1), max(d2,d3));
        for(int i0 = 0; i0 < dmax; i0 += 64){
            int li0 = (i0+f < d0) ? csr[s0+i0+f] : NN;
            int li1 = (i0+f < d1) ? csr[s1+i0+f] : NN;
            int li2 = (i0+f < d2) ? csr[s2+i0+f] : NN;
            int li3 = (i0+f < d3) ? csr[s3+i0+f] : NN;
            int mm = min(dmax - i0, 64);
            for(int j = 0; j < mm; j += 8){    // 32 independent line-gathers per step
                float t0 = 0.f, t1 = 0.f, t2 = 0.f, t3 = 0.f;
                #pragma unroll
                for(int u = 0; u < 8; u++){
                    int r0 = __builtin_amdgcn_readlane(li0, j+u);
                    int r1 = __builtin_amdgcn_readlane(li1, j+u);
                    int r2 = __builtin_amdgcn_readlane(li2, j+u);
                    int r3 = __builtin_amdgcn_readlane(li3, j+u);
                    t0 += (float)hb[(size_t)r0*64 + f];
                    t1 += (float)hb[(size_t)r1*64 + f];
                    t2 += (float)hb[(size_t)r2*64 + f];
                    t3 += (float)hb[(size_t)r3*64 + f];
                }
                a0 += t0; a1 += t1; a2 += t2; a3 += t3;
            }
        }
        float dn0 = dinv[na], dn1 = dinv[nb], dn2 = dinv[nc], dn3 = dinv[nd];
        float sf0 = (float)hb[(size_t)na*64 + f];
        float sf1 = (float)hb[(size_t)nb*64 + f];
        float sf2 = (float)hb[(size_t)nc*64 + f];
        float sf3 = (float)hb[(size_t)nd*64 + f];
        float o0 = fmaxf((a0 + sf0)*dn0 + bv, 0.f);
        float o1 = fmaxf((a1 + sf1)*dn1 + bv, 0.f);
        float o2 = fmaxf((a2 + sf2)*dn2 + bv, 0.f);
        float o3 = fmaxf((a3 + sf3)*dn3 + bv, 0.f);
        As[(rb+0)*PS + f] = (_Float16)o0;
        As[(rb+1)*PS + f] = (_Float16)o1;
        As[(rb+2)*PS + f] = (_Float16)o2;
        As[(rb+3)*PS + f] = (_Float16)o3;
        if(WRITEF){
            if(m0+rb+0 < NN) outf[(size_t)(m0+rb+0)*64 + f] = o0;
            if(m0+rb+1 < NN) outf[(size_t)(m0+rb+1)*64 + f] = o1;
            if(m0+rb+2 < NN) outf[(size_t)(m0+rb+2)*64 + f] = o2;
            if(m0+rb+3 < NN) outf[(size_t)(m0+rb+3)*64 + f] = o3;
        }
    }
    __syncthreads();
    // GEMM phase
    int l = t&63, lm = l&15, q = l>>4;
    f32x4 acc[NJH][4] = {};
    const _Float16* arow = &As[(w*16+lm)*PS + q*8];
    #pragma unroll
    for(int ks = 0; ks < 2; ks++){
        half8 a = *(const half8*)(arow + ks*32);
        #pragma unroll
        for(int h = 0; h < NJH; h++){
            const _Float16* brow = &Bs[h*64*PS + lm*PS + q*8] + ks*32;
            half8 b0 = *(const half8*)(brow);
            half8 b1 = *(const half8*)(brow + 16*PS);
            half8 b2 = *(const half8*)(brow + 32*PS);
            half8 b3 = *(const half8*)(brow + 48*PS);
            acc[h][0] = __builtin_amdgcn_mfma_f32_16x16x32_f16(a, b0, acc[h][0], 0,0,0);
            acc[h][1] = __builtin_amdgcn_mfma_f32_16x16x32_f16(a, b1, acc[h][1], 0,0,0);
            acc[h][2] = __builtin_amdgcn_mfma_f32_16x16x32_f16(a, b2, acc[h][2], 0,0,0);
            acc[h][3] = __builtin_amdgcn_mfma_f32_16x16x32_f16(a, b3, acc[h][3], 0,0,0);
        }
    }
    #pragma unroll
    for(int h = 0; h < NJH; h++){
        #pragma unroll
        for(int nt = 0; nt < 4; nt++){
            int jcol = h*64 + nt*16 + lm;
            float fs = FOLD ? fold[jcol] : 0.f;
            float fb = FOLD ? fold[NJH*64 + jcol] : 0.f;
            #pragma unroll
            for(int r = 0; r < 4; r++){
                int rowi = m0 + w*16 + q*4 + r;
                if(rowi >= NN) continue;
                float v = acc[h][nt][r];
                if(FOLD) v = v*fs + fb;
                if(SCALE) v *= dinv[rowi];
                outh[(size_t)rowi*(NJH*64) + jcol] = (_Float16)v;
            }
        }
    }
}

// ---------------- edge predictor: 256-node buckets, 32KB LDS B-tile ----------------
__global__ void __launch_bounds__(512) k_edgeb(const int* __restrict__ bcnt,
                                               const uint32* __restrict__ staged,
                                               const _Float16* __restrict__ pre,
                                               const float* __restrict__ w2,
                                               const float* __restrict__ b2,
                                               _Float16* __restrict__ zqh){
    __shared__ half8 Bl[BUCK*8];           // 32KB: bucket's preB, swizzled
    int t = threadIdx.x;
    int item = ((int)blockIdx.x & 7)*98 + ((int)blockIdx.x >> 3);
    int b = item >> 1, s = item & 1;
    const _Float16* ps = pre;
    for(int idx = t; idx < BUCK*8; idx += 512){
        int rl = idx >> 3, ch = idx & 7;
        int n = (b << BSH) + rl; if(n >= NN) n = NN-1;
        Bl[rl*8 + (ch ^ (rl & 7))] = *(const half8*)(ps + (size_t)n*128 + 64 + ch*8);
    }
    __syncthreads();

    int cnt = min(bcnt[b], BCAP);
    int lo = (cnt * s) >> 1, hi = (cnt * (s+1)) >> 1;
    const uint32* st = staged + (size_t)b*BCAP;
    _Float16* zb = zqh + (size_t)b*BCAP;
    int p  = t & 7;                        // part within octet (16B feature chunk)
    int oc = t >> 3;                       // block-wide octet id 0..63
    f32x8 w2v = *(const f32x8*)(w2 + 8*p); // 32B-aligned (p*32B)
    float b2v = b2[0];

    auto edot = [&](uint32 u)->float{
        int r  = (int)(u >> BSH);
        int cl = (int)(u & (BUCK-1));
        half8 av = *(const half8*)(ps + (size_t)r*128 + 8*p);   // preA chunk p (global gather)
        half8 bv = Bl[cl*8 + (p ^ (cl & 7))];                   // preB chunk p (LDS)
        half8 sv = av + bv;                                     // packed v_pk_add_f16
        half8 zero8 = {};
        half8 rv = __builtin_elementwise_max(sv, zero8);        // packed v_pk_max_f16
        f32x8 fv = __builtin_convertvector(rv, f32x8);
        float z;
        z  = fv[0]*w2v[0] + fv[1]*w2v[1];
        z  = fmaf(fv[2], w2v[2], z); z = fmaf(fv[3], w2v[3], z);
        z  = fmaf(fv[4], w2v[4], z); z = fmaf(fv[5], w2v[5], z);
        z  = fmaf(fv[6], w2v[6], z); z = fmaf(fv[7], w2v[7], z);
        return z;
    };

    int i = lo + oc;
    for(; i + 64 < hi; i += 128){          // 2 edges in flight per thread
        uint32 u0 = st[i], u1 = st[i+64];
        float z0 = edot(u0);
        float z1 = edot(u1);
        z0 += __shfl_xor(z0, 1, 64); z1 += __shfl_xor(z1, 1, 64);
        z0 += __shfl_xor(z0, 2, 64); z1 += __shfl_xor(z1, 2, 64);
        z0 += __shfl_xor(z0, 4, 64); z1 += __shfl_xor(z1, 4, 64);
        if(p == 0){
            zb[i]    = (_Float16)(1.f/(1.f+__expf(-(z0+b2v))));
            zb[i+64] = (_Float16)(1.f/(1.f+__expf(-(z1+b2v))));
        }
    }
    for(; i < hi; i += 64){
        uint32 u0 = st[i];
        float z0 = edot(u0);
        z0 += __shfl_xor(z0, 1, 64);
        z0 += __shfl_xor(z0, 2, 64);
        z0 += __shfl_xor(z0, 4, 64);
        if(p == 0) zb[i] = (_Float16)(1.f/(1.f+__expf(-(z0+b2v))));
    }
}

// ---------------- permute staged-order results back to edge order ----------------
__global__ void __launch_bounds__(256) k_final(const uint32* __restrict__ posE,
                                               const _Float16* __restrict__ zqh,
                                               float* __restrict__ out){
    int e = blockIdx.x*256 + threadIdx.x;
    if(e < NE){
        uint32 pz = posE[e];
        out[e] = (float)zqh[pz < (uint32)(NBUCK*BCAP) ? pz : 0u];
    }
}

// ---------------- launch ----------------

extern "C" void kernel_launch(void* const* d_in, const int* in_sizes, int n_in,
                              void* d_out, int out_size, void* d_ws, size_t ws_size,
                              hipStream_t stream){
    const float* x   = (const float*)d_in[0];
    const int* ei    = (const int*)d_in[1];
    const int* row   = ei;
    const int* col   = ei + NE;
    const float* encW = (const float*)d_in[2],  *encB = (const float*)d_in[3];
    const float* encG = (const float*)d_in[4],  *encBe= (const float*)d_in[5];
    const float* encM = (const float*)d_in[6],  *encV = (const float*)d_in[7];
    const float* c1W  = (const float*)d_in[8],  *c1b  = (const float*)d_in[9];
    const float* c2W  = (const float*)d_in[10], *c2b  = (const float*)d_in[11];
    const float* ep1W = (const float*)d_in[12], *ep1b = (const float*)d_in[13];
    const float* epG  = (const float*)d_in[14], *epBe = (const float*)d_in[15];
    const float* epM  = (const float*)d_in[16], *epV  = (const float*)d_in[17];
    const float* ep2W = (const float*)d_in[18], *ep2b = (const float*)d_in[19];

    char* wsc = (char*)d_ws;
    size_t o = 0;
    auto alloc = [&](size_t bytes)->void*{
        void* p = wsc + o; o += (bytes + 255) & ~(size_t)255; return p;
    };
    int*      deg     = (int*)     alloc((size_t)NN*4);
    int*      starts  = (int*)     alloc((size_t)NN*4);
    int*      bcnt    = (int*)     alloc((size_t)NBUCK*4);
    int*      csr     = (int*)     alloc((size_t)NE*4);
    uint32*   staged  = (uint32*)  alloc((size_t)NBUCK*BCAP*4);   // 8.0 MB
    float*    dinv    = (float*)   alloc((size_t)NN*4);
    float*    foldEnc = (float*)   alloc(128*4);
    float*    foldPre = (float*)   alloc(256*4);
    _Float16* wt      = (_Float16*)alloc(24576*2);                // fp16 transposed weights
    _Float16* bufA    = (_Float16*)alloc((size_t)NN*64*2);        // fp16 h0 buffer (12.8 MB)
    _Float16* bufB    = (_Float16*)alloc((size_t)(NN+1)*64*2);    // fp16 hw1' + zero row NN
    _Float16* bufB2   = (_Float16*)alloc((size_t)(NN+1)*64*2);    // fp16 hw2' + zero row NN
    _Float16* preh    = (_Float16*)alloc((size_t)NN*128*2);       // fp16 pre [A|B] (25.6 MB)
    uint32*   posE    = (uint32*)  alloc((size_t)NE*4);           // edge -> staged slot (6.4 MB)
    _Float16* zqh     = (_Float16*)alloc((size_t)NBUCK*BCAP*2);   // staged-order sigmoid (4.0 MB)

    float* outp = (float*)d_out;               // [NN*64] node emb | [NE] edge preds
    float* node_out = outp;
    float* edge_out = outp + (size_t)NN*64;

    // bcnt must be zero before k_pp (part blocks atomically reserve into it)
    hipMemsetAsync(bcnt, 0, (size_t)NBUCK*4, stream);
    // fused: edge partition (391 blocks) || weight/BN prep (97 blocks)
    k_pp <<<NCHUNK + 97, 256, 0, stream>>>(row, col, bcnt, staged, posE,
                                           encW, c1W, c2W, ep1W, wt,
                                           encB, encG, encBe, encM, encV,
                                           ep1b, epG, epBe, epM, epV,
                                           foldEnc, foldPre,
                                           bufB + (size_t)NN*64, bufB2 + (size_t)NN*64);
    // fused: csr build (392 blocks) || encoder GEMM (1563 blocks)
    k_fe <<<NBUCK + NB_MF, 256, 0, stream>>>(bcnt, staged, deg, starts, dinv, csr,
                                             x, wt, foldEnc, bufA);

    // conv1 GEMM: hw1' = (h0 @ c1W) * dinv -> bufB
    k_mfc1<<<NB_MF, 256, 0, stream>>>(bufA, wt + 8192, dinv, bufB);

    // fused agg1 + conv2 GEMM: gather bufB -> h1 tile (LDS) -> hw2' = (h1@c2W)*dinv -> bufB2
    k_aggmm<1,true,false,false><<<NB_MF, 256, 0, stream>>>
        (bufB, starts, deg, csr, dinv, c1b, wt + 12288, nullptr, nullptr, bufB2);

    // fused agg2 + edge-pre GEMM: gather bufB2 -> h2 tile (LDS) + fp32 node_out;
    // pre[n] = [sp*(h2@W1top)+cst | sp*(h2@W1bot)] -> preh (both halves per block)
    k_aggmm<2,false,true,true><<<NB_MF, 256, 0, stream>>>
        (bufB2, starts, deg, csr, dinv, c2b, wt + 16384, foldPre, node_out, preh);

    // per-edge MLP in staged order: B-half from LDS, A-half random gather
    k_edgeb<<<NEB, 512, 0, stream>>>(bcnt, staged, (const _Float16*)preh, ep2W, ep2b, zqh);
    // permute back to edge order
    k_final<<<NFB, 256, 0, stream>>>(posE, zqh, edge_out);
}

// Round 12
// 318.932 us; speedup vs baseline: 1.1152x; 1.1152x over previous
//
#include <hip/hip_runtime.h>
#include <hip/hip_bf16.h>
#include <hip/hip_fp16.h>

#define NN 100000
#define NE 1600000
#define FIN 128
#define HD 64
#define NB_MF 1563     // ceil(NN/64): 64-row tiles
#define BSH 8          // bucket covers 256 dest nodes (32KB preB tile)
#define BUCK 256
#define NBUCK 392      // ceil(NN/256)=391, padded to 392 so NEB=784=8*98 (bijective XCD swizzle)
#define BCAP 5120      // per-bucket staging cap (mean 4082, sigma 64 -> +16 sigma)
#define CHUNK 4096     // edges per stage-1 block (391 blocks; LDS counting sort per block)
#define NCHUNK 391     // ceil(NE/CHUNK)
#define ESPLIT 2       // edge-kernel blocks per bucket
#define NEB (NBUCK*ESPLIT)   // 784 = 8*98 (XCD-swizzlable)
#define NFB 6250       // k_final blocks: 6250*256 = NE exactly
#define NAGG 6250      // k_agg4 blocks: 16 nodes/block

typedef unsigned int uint32;
typedef _Float16 half8 __attribute__((ext_vector_type(8)));
typedef float f32x4 __attribute__((ext_vector_type(4)));
typedef float f32x8 __attribute__((ext_vector_type(8)));

// ---------------- fused launch 1: k_pp = k_part (blocks 0..390) + prep (blocks 391..487) ----------
// part: per-block LDS counting sort -> coalesced run writes. prep: weight fp16-transpose +
// BN folds + bufB dummy zero row. bcnt zeroed by hipMemsetAsync BEFORE this launch.
__global__ void __launch_bounds__(256) k_pp(const int* __restrict__ row,
                                            const int* __restrict__ col,
                                            int* __restrict__ bcnt,
                                            uint32* __restrict__ staged,
                                            uint32* __restrict__ posE,
                                            const float* __restrict__ encW, const float* __restrict__ c1W,
                                            const float* __restrict__ c2W, const float* __restrict__ ep1W,
                                            _Float16* __restrict__ wt,
                                            const float* __restrict__ encB, const float* __restrict__ encG,
                                            const float* __restrict__ encBe, const float* __restrict__ encM,
                                            const float* __restrict__ encV,
                                            const float* __restrict__ ep1b, const float* __restrict__ epG,
                                            const float* __restrict__ epBe, const float* __restrict__ epM,
                                            const float* __restrict__ epV,
                                            float* __restrict__ foldEnc, float* __restrict__ foldPre,
                                            _Float16* __restrict__ bufBzero){
    int blk = blockIdx.x, t = threadIdx.x;
    if(blk < NCHUNK){
        // ---- k_part body ----
        __shared__ int h[512];          // counts -> start cursor
        __shared__ int sc[512];         // inclusive scan -> dstbase
        __shared__ int gb[512];         // global base per bucket
        __shared__ uint32 lcsr[CHUNK];  // bucket-sorted packed edges (16KB)
        __shared__ int dst[CHUNK];      // global slot per sorted element (16KB)
        int e0 = blk * CHUNK;
        int e1 = min(e0 + CHUNK, NE);
        h[t] = 0; h[256+t] = 0;
        __syncthreads();
        for(int e = e0 + t; e < e1; e += 256)
            atomicAdd(&h[col[e] >> BSH], 1);
        __syncthreads();
        int c0 = h[t], c1 = h[256+t];
        int i2 = 256 + t;
        gb[t]  = (c0 > 0) ? atomicAdd(&bcnt[t], c0) : 0;
        gb[i2] = (i2 < NBUCK && c1 > 0) ? atomicAdd(&bcnt[i2], c1) : 0;
        sc[t] = c0; __syncthreads();
        for(int off = 1; off < 256; off <<= 1){
            int a = (t >= off) ? sc[t-off] : 0;
            __syncthreads();
            sc[t] += a;
            __syncthreads();
        }
        int sum0 = sc[255];
        __syncthreads();
        sc[i2] = c1; __syncthreads();
        for(int off = 1; off < 256; off <<= 1){
            int a = (t >= off) ? sc[i2-off] : 0;
            __syncthreads();
            sc[i2] += a;
            __syncthreads();
        }
        __syncthreads();
        {
            int st0 = sc[t] - c0;
            int st1 = sc[i2] + sum0 - c1;
            h[t]   = st0;
            h[i2]  = st1;
            sc[t]  = t*BCAP  + gb[t]  - st0;
            sc[i2] = i2*BCAP + gb[i2] - st1;
        }
        __syncthreads();
        for(int e = e0 + t; e < e1; e += 256){
            int c = col[e], r = row[e];
            int b = c >> BSH;
            int p = atomicAdd(&h[b], 1);
            lcsr[p] = ((uint32)r << BSH) | (uint32)(c & (BUCK-1));
            int slot = sc[b] + p;
            int off  = slot - b*BCAP;
            bool ok  = (off < BCAP);
            dst[p]   = ok ? slot : -1;
            posE[e]  = ok ? (uint32)slot : 0xFFFFFFFFu;
        }
        __syncthreads();
        int cnt = e1 - e0;
        for(int i = t; i < cnt; i += 256){
            int d = dst[i];
            if(d >= 0) staged[d] = lcsr[i];
        }
    } else {
        // ---- prep body ----
        int pblk = blk - NCHUNK;
        if(pblk < 96){
            int i = pblk*256 + t;   // 96*256 = 24576
            if(i < 8192){
                int n = i >> 7, k = i & 127;
                wt[i] = (_Float16)encW[k*64 + n];
            } else if(i < 12288){
                int j = i - 8192; int n = j >> 6, k = j & 63;
                wt[i] = (_Float16)c1W[k*64 + n];
            } else if(i < 16384){
                int j = i - 12288; int n = j >> 6, k = j & 63;
                wt[i] = (_Float16)c2W[k*64 + n];
            } else {
                int j = i - 16384; int hh = j >> 12; int jj = j & 4095;
                int n = jj >> 6, k = jj & 63;
                wt[i] = (_Float16)ep1W[(hh*64 + k)*64 + n];   // logical W[k][hh*64+n]
            }
        } else {
            if(t < 64){
                int j = t;
                float s = encG[j]*rsqrtf(encV[j]+1e-5f);
                foldEnc[j]      = s;
                foldEnc[64+j]   = (encB[j]-encM[j])*s + encBe[j];
                float sp = epG[j]*rsqrtf(epV[j]+1e-5f);
                foldPre[j]      = sp;
                foldPre[64+j]   = sp;
                foldPre[128+j]  = sp*(ep1b[j]-epM[j]) + epBe[j];
                foldPre[192+j]  = 0.f;
                bufBzero[j]     = (_Float16)0.f;   // dummy zero row for k_agg4
            }
        }
    }
}

// ---------------- fused launch 2: k_fe = k_fill3 (blocks 0..391) + encoder mfma (392..1954) ------
// fill3 and encoder have disjoint inputs (bcnt/staged vs wt/foldEnc/x) -> overlap in one launch.
// LDS shared via union: max(23KB, 34KB) = 34KB, preserving encoder occupancy.
__global__ void __launch_bounds__(256) k_fe(const int* __restrict__ bcnt,
                                            const uint32* __restrict__ staged,
                                            int* __restrict__ deg,
                                            int* __restrict__ starts,
                                            float* __restrict__ dinv,
                                            int* __restrict__ csr,
                                            const float* __restrict__ x,
                                            const _Float16* __restrict__ wt,
                                            const float* __restrict__ foldEnc,
                                            _Float16* __restrict__ bufA){
    __shared__ union U {
        struct { int h[BUCK]; int sc[BUCK]; int red[256]; int lcsr[BCAP]; } f;   // 23KB
        struct { _Float16 As[64*136]; _Float16 Bs[64*136]; } m;                  // 34KB
    } sh;
    int blk = blockIdx.x, t = threadIdx.x;
    if(blk < NBUCK){
        // ---- fill3 body ----
        int b = blk;
        int part = 0;
        for(int i = t; i < b; i += 256) part += min(bcnt[i], BCAP);
        sh.f.red[t] = part; __syncthreads();
        for(int off = 128; off > 0; off >>= 1){
            if(t < off) sh.f.red[t] += sh.f.red[t+off];
            __syncthreads();
        }
        int base = sh.f.red[0];
        sh.f.h[t] = 0;
        __syncthreads();
        int cnt = min(bcnt[b], BCAP);
        const uint32* st = staged + (size_t)b*BCAP;
        for(int i = t; i < cnt; i += 256) atomicAdd(&sh.f.h[st[i] & (BUCK-1)], 1);
        __syncthreads();
        int v = sh.f.h[t];
        sh.f.sc[t] = v; __syncthreads();
        for(int off = 1; off < 256; off <<= 1){
            int a = (t >= off) ? sh.f.sc[t-off] : 0;
            __syncthreads();
            sh.f.sc[t] += a;
            __syncthreads();
        }
        int ex = sh.f.sc[t] - v;
        int n = b*BUCK + t;
        if(n < NN){
            deg[n]    = v;
            starts[n] = base + ex;
            dinv[n]   = rsqrtf((float)(v + 1));   // +1 self-loop
        }
        sh.f.h[t] = ex;
        __syncthreads();
        for(int i = t; i < cnt; i += 256){
            uint32 u = st[i];
            int p = atomicAdd(&sh.f.h[u & (BUCK-1)], 1);
            sh.f.lcsr[p] = (int)(u >> BSH);
        }
        __syncthreads();
        for(int i = t; i < cnt; i += 256) csr[base + i] = sh.f.lcsr[i];
    } else {
        // ---- encoder mfma body: K=128, A fp32 (cvt in stage), fold+relu, OS=64 ----
        constexpr int K = FIN, PS = K + 8;
        int m0 = (blk - NBUCK)*64;
        for(int idx = t; idx < 64*(K/8); idx += 256){
            int n = idx/(K/8), c = idx%(K/8);
            *(half8*)&sh.m.Bs[n*PS + c*8] = *(const half8*)&wt[n*K + c*8];
        }
        for(int idx = t; idx < 64*(K/4); idx += 256){
            int r = idx/(K/4), c = idx%(K/4);
            int rowi = m0 + r; if(rowi >= NN) rowi = NN-1;
            float4 v = *(const float4*)&x[(size_t)rowi*K + c*4];
            _Float16* d = &sh.m.As[r*PS + c*4];
            d[0]=(_Float16)v.x; d[1]=(_Float16)v.y; d[2]=(_Float16)v.z; d[3]=(_Float16)v.w;
        }
        __syncthreads();
        int w = t>>6, l = t&63;
        int lm = l&15, q = l>>4;
        f32x4 acc0 = {0.f,0.f,0.f,0.f}, acc1 = {0.f,0.f,0.f,0.f};
        f32x4 acc2 = {0.f,0.f,0.f,0.f}, acc3 = {0.f,0.f,0.f,0.f};
        const _Float16* arow = &sh.m.As[(w*16+lm)*PS + q*8];
        const _Float16* brow = &sh.m.Bs[lm*PS + q*8];
        #pragma unroll
        for(int ks = 0; ks < K/32; ks++){
            half8 a  = *(const half8*)(arow + ks*32);
            half8 b0 = *(const half8*)(brow + ks*32);
            half8 b1 = *(const half8*)(brow + 16*PS + ks*32);
            half8 b2 = *(const half8*)(brow + 32*PS + ks*32);
            half8 b3 = *(const half8*)(brow + 48*PS + ks*32);
            acc0 = __builtin_amdgcn_mfma_f32_16x16x32_f16(a, b0, acc0, 0,0,0);
            acc1 = __builtin_amdgcn_mfma_f32_16x16x32_f16(a, b1, acc1, 0,0,0);
            acc2 = __builtin_amdgcn_mfma_f32_16x16x32_f16(a, b2, acc2, 0,0,0);
            acc3 = __builtin_amdgcn_mfma_f32_16x16x32_f16(a, b3, acc3, 0,0,0);
        }
        f32x4 accs[4] = {acc0, acc1, acc2, acc3};
        #pragma unroll
        for(int nt = 0; nt < 4; nt++){
            int jcol = nt*16 + lm;
            float fs = foldEnc[jcol];
            float fb = foldEnc[64 + jcol];
            #pragma unroll
            for(int r = 0; r < 4; r++){
                int rowi = m0 + w*16 + q*4 + r;
                if(rowi >= NN) continue;
                float v = accs[nt][r]*fs + fb;
                v = fmaxf(v, 0.f);
                bufA[(size_t)rowi*64 + jcol] = (_Float16)v;
            }
        }
    }
}

// ---------------- MFMA GEMM: 64 rows x 64 cols per block, K fully in LDS ----------------
template<int K, bool AF32, bool FOLD, bool RELU, bool SCALE, int OS>
__global__ void __launch_bounds__(256) k_mfma(const void* __restrict__ Ain,
                                              const _Float16* __restrict__ Bt,
                                              const float* __restrict__ fold,
                                              const float* __restrict__ rowscale,
                                              _Float16* __restrict__ outh){
    constexpr int PS = K + 8;              // padded row stride (halves); row bytes %16==0
    __shared__ _Float16 As[64*PS];
    __shared__ _Float16 Bs[64*PS];
    int t = threadIdx.x;
    int m0 = blockIdx.x*64;
    int jh = blockIdx.y;
    // stage B (transposed fp16 [64][K], contiguous in global)
    {
        const _Float16* src = Bt + (size_t)jh*64*K;
        for(int idx = t; idx < 64*(K/8); idx += 256){
            int n = idx/(K/8), c = idx%(K/8);
            *(half8*)&Bs[n*PS + c*8] = *(const half8*)&src[n*K + c*8];
        }
    }
    // stage A
    if(AF32){
        const float* A = (const float*)Ain;
        for(int idx = t; idx < 64*(K/4); idx += 256){
            int r = idx/(K/4), c = idx%(K/4);
            int rowi = m0 + r; if(rowi >= NN) rowi = NN-1;
            float4 v = *(const float4*)&A[(size_t)rowi*K + c*4];
            _Float16* d = &As[r*PS + c*4];
            d[0]=(_Float16)v.x; d[1]=(_Float16)v.y; d[2]=(_Float16)v.z; d[3]=(_Float16)v.w;
        }
    } else {
        const _Float16* A = (const _Float16*)Ain;
        for(int idx = t; idx < 64*(K/8); idx += 256){
            int r = idx/(K/8), c = idx%(K/8);
            int rowi = m0 + r; if(rowi >= NN) rowi = NN-1;
            *(half8*)&As[r*PS + c*8] = *(const half8*)&A[(size_t)rowi*K + c*8];
        }
    }
    __syncthreads();
    int w = t>>6, l = t&63;
    int lm = l&15, q = l>>4;
    f32x4 acc0 = {0.f,0.f,0.f,0.f}, acc1 = {0.f,0.f,0.f,0.f};
    f32x4 acc2 = {0.f,0.f,0.f,0.f}, acc3 = {0.f,0.f,0.f,0.f};
    const _Float16* arow = &As[(w*16+lm)*PS + q*8];
    const _Float16* brow = &Bs[lm*PS + q*8];
    #pragma unroll
    for(int ks = 0; ks < K/32; ks++){
        half8 a  = *(const half8*)(arow + ks*32);
        half8 b0 = *(const half8*)(brow + ks*32);
        half8 b1 = *(const half8*)(brow + 16*PS + ks*32);
        half8 b2 = *(const half8*)(brow + 32*PS + ks*32);
        half8 b3 = *(const half8*)(brow + 48*PS + ks*32);
        acc0 = __builtin_amdgcn_mfma_f32_16x16x32_f16(a, b0, acc0, 0,0,0);
        acc1 = __builtin_amdgcn_mfma_f32_16x16x32_f16(a, b1, acc1, 0,0,0);
        acc2 = __builtin_amdgcn_mfma_f32_16x16x32_f16(a, b2, acc2, 0,0,0);
        acc3 = __builtin_amdgcn_mfma_f32_16x16x32_f16(a, b3, acc3, 0,0,0);
    }
    f32x4 accs[4] = {acc0, acc1, acc2, acc3};
    #pragma unroll
    for(int nt = 0; nt < 4; nt++){
        int col = nt*16 + lm;
        int jcol = jh*64 + col;
        float fs = FOLD ? fold[jcol] : 0.f;
        float fb = FOLD ? fold[OS + jcol] : 0.f;
        #pragma unroll
        for(int r = 0; r < 4; r++){
            int rowi = m0 + w*16 + q*4 + r;
            if(rowi >= NN) continue;
            float v = accs[nt][r];
            if(FOLD) v = v*fs + fb;
            if(RELU) v = fmaxf(v, 0.f);
            if(SCALE) v *= rowscale[rowi];
            outh[(size_t)rowi*OS + jcol] = (_Float16)v;
        }
    }
}

// ---------------- GCN aggregation: 4 nodes per wave, 32 gathers in flight ----------------
__global__ void __launch_bounds__(256) k_agg4(const _Float16* __restrict__ hb,
                                              const int* __restrict__ starts,
                                              const int* __restrict__ deg,
                                              const int* __restrict__ csr,
                                              const float* __restrict__ dinv,
                                              const float* __restrict__ bias,
                                              _Float16* __restrict__ outh,
                                              float* __restrict__ outf){
    int t = threadIdx.x, w = t>>6, f = t&63;
    int n0 = blockIdx.x*16 + w*4;          // 4 consecutive nodes per wave
    int s0 = __builtin_amdgcn_readfirstlane(starts[n0+0]);
    int s1 = __builtin_amdgcn_readfirstlane(starts[n0+1]);
    int s2 = __builtin_amdgcn_readfirstlane(starts[n0+2]);
    int s3 = __builtin_amdgcn_readfirstlane(starts[n0+3]);
    int d0 = __builtin_amdgcn_readfirstlane(deg[n0+0]);
    int d1 = __builtin_amdgcn_readfirstlane(deg[n0+1]);
    int d2 = __builtin_amdgcn_readfirstlane(deg[n0+2]);
    int d3 = __builtin_amdgcn_readfirstlane(deg[n0+3]);
    float a0 = 0.f, a1 = 0.f, a2 = 0.f, a3 = 0.f;
    int dmax = max(max(d0,d1), max(d2,d3));
    for(int i0 = 0; i0 < dmax; i0 += 64){
        int li0 = (i0+f < d0) ? csr[s0+i0+f] : NN;
        int li1 = (i0+f < d1) ? csr[s1+i0+f] : NN;
        int li2 = (i0+f < d2) ? csr[s2+i0+f] : NN;
        int li3 = (i0+f < d3) ? csr[s3+i0+f] : NN;
        int mm = min(dmax - i0, 64);
        for(int j = 0; j < mm; j += 8){    // 32 independent line-gathers per step
            float t0 = 0.f, t1 = 0.f, t2 = 0.f, t3 = 0.f;
            #pragma unroll
            for(int u = 0; u < 8; u++){
                int r0 = __builtin_amdgcn_readlane(li0, j+u);
                int r1 = __builtin_amdgcn_readlane(li1, j+u);
                int r2 = __builtin_amdgcn_readlane(li2, j+u);
                int r3 = __builtin_amdgcn_readlane(li3, j+u);
                t0 += (float)hb[(size_t)r0*64 + f];
                t1 += (float)hb[(size_t)r1*64 + f];
                t2 += (float)hb[(size_t)r2*64 + f];
                t3 += (float)hb[(size_t)r3*64 + f];
            }
            a0 += t0; a1 += t1; a2 += t2; a3 += t3;
        }
    }
    float bv = bias[f];
    float dn0 = dinv[n0+0], dn1 = dinv[n0+1], dn2 = dinv[n0+2], dn3 = dinv[n0+3];
    float sf0 = (float)hb[(size_t)(n0+0)*64 + f];
    float sf1 = (float)hb[(size_t)(n0+1)*64 + f];
    float sf2 = (float)hb[(size_t)(n0+2)*64 + f];
    float sf3 = (float)hb[(size_t)(n0+3)*64 + f];
    float o0 = fmaxf((a0 + sf0)*dn0 + bv, 0.f);
    float o1 = fmaxf((a1 + sf1)*dn1 + bv, 0.f);
    float o2 = fmaxf((a2 + sf2)*dn2 + bv, 0.f);
    float o3 = fmaxf((a3 + sf3)*dn3 + bv, 0.f);
    outh[(size_t)(n0+0)*64 + f] = (_Float16)o0;
    outh[(size_t)(n0+1)*64 + f] = (_Float16)o1;
    outh[(size_t)(n0+2)*64 + f] = (_Float16)o2;
    outh[(size_t)(n0+3)*64 + f] = (_Float16)o3;
    if(outf){
        outf[(size_t)(n0+0)*64 + f] = o0;
        outf[(size_t)(n0+1)*64 + f] = o1;
        outf[(size_t)(n0+2)*64 + f] = o2;
        outf[(size_t)(n0+3)*64 + f] = o3;
    }
}

// ---------------- edge predictor: 256-node buckets, 32KB LDS B-tile ----------------
__global__ void __launch_bounds__(512) k_edgeb(const int* __restrict__ bcnt,
                                               const uint32* __restrict__ staged,
                                               const _Float16* __restrict__ pre,
                                               const float* __restrict__ w2,
                                               const float* __restrict__ b2,
                                               _Float16* __restrict__ zqh){
    __shared__ half8 Bl[BUCK*8];           // 32KB: bucket's preB, swizzled
    int t = threadIdx.x;
    int item = ((int)blockIdx.x & 7)*98 + ((int)blockIdx.x >> 3);
    int b = item >> 1, s = item & 1;
    const _Float16* ps = pre;
    for(int idx = t; idx < BUCK*8; idx += 512){
        int rl = idx >> 3, ch = idx & 7;
        int n = (b << BSH) + rl; if(n >= NN) n = NN-1;
        Bl[rl*8 + (ch ^ (rl & 7))] = *(const half8*)(ps + (size_t)n*128 + 64 + ch*8);
    }
    __syncthreads();

    int cnt = min(bcnt[b], BCAP);
    int lo = (cnt * s) >> 1, hi = (cnt * (s+1)) >> 1;
    const uint32* st = staged + (size_t)b*BCAP;
    _Float16* zb = zqh + (size_t)b*BCAP;
    int p  = t & 7;                        // part within octet (16B feature chunk)
    int oc = t >> 3;                       // block-wide octet id 0..63
    f32x8 w2v = *(const f32x8*)(w2 + 8*p); // 32B-aligned (p*32B)
    float b2v = b2[0];

    auto edot = [&](uint32 u)->float{
        int r  = (int)(u >> BSH);
        int cl = (int)(u & (BUCK-1));
        half8 av = *(const half8*)(ps + (size_t)r*128 + 8*p);   // preA chunk p (global gather)
        half8 bv = Bl[cl*8 + (p ^ (cl & 7))];                   // preB chunk p (LDS)
        half8 sv = av + bv;                                     // packed v_pk_add_f16
        half8 zero8 = {};
        half8 rv = __builtin_elementwise_max(sv, zero8);        // packed v_pk_max_f16
        f32x8 fv = __builtin_convertvector(rv, f32x8);
        float z;
        z  = fv[0]*w2v[0] + fv[1]*w2v[1];
        z  = fmaf(fv[2], w2v[2], z); z = fmaf(fv[3], w2v[3], z);
        z  = fmaf(fv[4], w2v[4], z); z = fmaf(fv[5], w2v[5], z);
        z  = fmaf(fv[6], w2v[6], z); z = fmaf(fv[7], w2v[7], z);
        return z;
    };

    int i = lo + oc;
    for(; i + 64 < hi; i += 128){          // 2 edges in flight per thread
        uint32 u0 = st[i], u1 = st[i+64];
        float z0 = edot(u0);
        float z1 = edot(u1);
        z0 += __shfl_xor(z0, 1, 64); z1 += __shfl_xor(z1, 1, 64);
        z0 += __shfl_xor(z0, 2, 64); z1 += __shfl_xor(z1, 2, 64);
        z0 += __shfl_xor(z0, 4, 64); z1 += __shfl_xor(z1, 4, 64);
        if(p == 0){
            zb[i]    = (_Float16)(1.f/(1.f+__expf(-(z0+b2v))));
            zb[i+64] = (_Float16)(1.f/(1.f+__expf(-(z1+b2v))));
        }
    }
    for(; i < hi; i += 64){
        uint32 u0 = st[i];
        float z0 = edot(u0);
        z0 += __shfl_xor(z0, 1, 64);
        z0 += __shfl_xor(z0, 2, 64);
        z0 += __shfl_xor(z0, 4, 64);
        if(p == 0) zb[i] = (_Float16)(1.f/(1.f+__expf(-(z0+b2v))));
    }
}

// ---------------- permute staged-order results back to edge order ----------------
__global__ void __launch_bounds__(256) k_final(const uint32* __restrict__ posE,
                                               const _Float16* __restrict__ zqh,
                                               float* __restrict__ out){
    int e = blockIdx.x*256 + threadIdx.x;
    if(e < NE){
        uint32 pz = posE[e];
        out[e] = (float)zqh[pz < (uint32)(NBUCK*BCAP) ? pz : 0u];
    }
}

// ---------------- launch ----------------

extern "C" void kernel_launch(void* const* d_in, const int* in_sizes, int n_in,
                              void* d_out, int out_size, void* d_ws, size_t ws_size,
                              hipStream_t stream){
    const float* x   = (const float*)d_in[0];
    const int* ei    = (const int*)d_in[1];
    const int* row   = ei;
    const int* col   = ei + NE;
    const float* encW = (const float*)d_in[2],  *encB = (const float*)d_in[3];
    const float* encG = (const float*)d_in[4],  *encBe= (const float*)d_in[5];
    const float* encM = (const float*)d_in[6],  *encV = (const float*)d_in[7];
    const float* c1W  = (const float*)d_in[8],  *c1b  = (const float*)d_in[9];
    const float* c2W  = (const float*)d_in[10], *c2b  = (const float*)d_in[11];
    const float* ep1W = (const float*)d_in[12], *ep1b = (const float*)d_in[13];
    const float* epG  = (const float*)d_in[14], *epBe = (const float*)d_in[15];
    const float* epM  = (const float*)d_in[16], *epV  = (const float*)d_in[17];
    const float* ep2W = (const float*)d_in[18], *ep2b = (const float*)d_in[19];

    char* wsc = (char*)d_ws;
    size_t o = 0;
    auto alloc = [&](size_t bytes)->void*{
        void* p = wsc + o; o += (bytes + 255) & ~(size_t)255; return p;
    };
    int*      deg     = (int*)     alloc((size_t)NN*4);
    int*      starts  = (int*)     alloc((size_t)NN*4);
    int*      bcnt    = (int*)     alloc((size_t)NBUCK*4);
    int*      csr     = (int*)     alloc((size_t)NE*4);
    uint32*   staged  = (uint32*)  alloc((size_t)NBUCK*BCAP*4);   // 8.0 MB
    float*    dinv    = (float*)   alloc((size_t)NN*4);
    float*    foldEnc = (float*)   alloc(128*4);
    float*    foldPre = (float*)   alloc(256*4);
    _Float16* wt      = (_Float16*)alloc(24576*2);                // fp16 transposed weights
    _Float16* bufA    = (_Float16*)alloc((size_t)NN*64*2);        // fp16 h buffer (12.8 MB)
    _Float16* bufB    = (_Float16*)alloc((size_t)(NN+1)*64*2);    // fp16 hw' buffer + zero row NN
    _Float16* preh    = (_Float16*)alloc((size_t)NN*128*2);       // fp16 pre [A|B] (25.6 MB)
    uint32*   posE    = (uint32*)  alloc((size_t)NE*4);           // edge -> staged slot (6.4 MB)
    _Float16* zqh     = (_Float16*)alloc((size_t)NBUCK*BCAP*2);   // staged-order sigmoid (4.0 MB)

    float* outp = (float*)d_out;               // [NN*64] node emb | [NE] edge preds
    float* node_out = outp;
    float* edge_out = outp + (size_t)NN*64;

    // bcnt must be zero before k_pp (part blocks atomically reserve into it)
    hipMemsetAsync(bcnt, 0, (size_t)NBUCK*4, stream);
    // fused: edge partition (391 blocks) || weight/BN prep (97 blocks)
    k_pp <<<NCHUNK + 97, 256, 0, stream>>>(row, col, bcnt, staged, posE,
                                           encW, c1W, c2W, ep1W, wt,
                                           encB, encG, encBe, encM, encV,
                                           ep1b, epG, epBe, epM, epV,
                                           foldEnc, foldPre, bufB + (size_t)NN*64);
    // fused: csr build (392 blocks) || encoder GEMM (1563 blocks)
    k_fe <<<NBUCK + NB_MF, 256, 0, stream>>>(bcnt, staged, deg, starts, dinv, csr,
                                             x, wt, foldEnc, bufA);

    // conv1: hw' = (h0 @ c1W) * dinv -> fp16 bufB; aggregate -> h1 fp16 bufA
    k_mfma<64,false,false,false,true,64><<<dim3(NB_MF,1), 256, 0, stream>>>
        (bufA, wt + 8192, nullptr, dinv, bufB);
    k_agg4 <<<NAGG, 256, 0, stream>>>(bufB, starts, deg, csr, dinv, c1b,
                                      bufA, nullptr);

    // conv2: -> h2 fp16 bufA + fp32 node_out (d_out)
    k_mfma<64,false,false,false,true,64><<<dim3(NB_MF,1), 256, 0, stream>>>
        (bufA, wt + 12288, nullptr, dinv, bufB);
    k_agg4 <<<NAGG, 256, 0, stream>>>(bufB, starts, deg, csr, dinv, c2b,
                                      bufA, node_out);

    // edge predictor precompute: pre[n] = [s*(h2@W1top)+cst | s*(h2@W1bot)] fp16 (jh = blockIdx.y)
    k_mfma<64,false,true,false,false,128><<<dim3(NB_MF,2), 256, 0, stream>>>
        (bufA, wt + 16384, foldPre, nullptr, preh);

    // per-edge MLP in staged order: B-half from LDS, A-half random gather
    k_edgeb<<<NEB, 512, 0, stream>>>(bcnt, staged, (const _Float16*)preh, ep2W, ep2b, zqh);
    // permute back to edge order
    k_final<<<NFB, 256, 0, stream>>>(posE, zqh, edge_out);
}